// Round 1
// baseline (11.317 us; speedup 1.0000x reference)
//
#include <hip/hip_runtime.h>

// Sampler forward: y = stop_gradient(1 - p) + p  ==  (1 - p) + p  ==  1.0f
// (forward value of the straight-through estimator is constant; p in [0,1],
//  no NaN/Inf possible since each sampled candidate's segment sum >= its own
//  exp term > 0). The whole gather/segment-softmax pipeline is gradient-only
//  dead code in the forward pass, so the kernel is a constant fill.

__global__ void __launch_bounds__(256)
sampler_fill_ones_vec4(float4* __restrict__ out4, int n4) {
    int i = blockIdx.x * blockDim.x + threadIdx.x;
    if (i < n4) {
        out4[i] = make_float4(1.0f, 1.0f, 1.0f, 1.0f);
    }
}

__global__ void __launch_bounds__(64)
sampler_fill_ones_tail(float* __restrict__ out, int start, int n) {
    int i = start + blockIdx.x * blockDim.x + threadIdx.x;
    if (i < n) {
        out[i] = 1.0f;
    }
}

extern "C" void kernel_launch(void* const* d_in, const int* in_sizes, int n_in,
                              void* d_out, int out_size, void* d_ws, size_t ws_size,
                              hipStream_t stream) {
    float* out = (float*)d_out;

    int n  = out_size;          // N_SAMP = 2,000,000
    int n4 = n >> 2;            // float4 chunks (500,000)
    int tail_start = n4 << 2;
    int tail = n - tail_start;  // 0 for this problem size

    if (n4 > 0) {
        int blocks = (n4 + 255) / 256;
        sampler_fill_ones_vec4<<<blocks, 256, 0, stream>>>((float4*)out, n4);
    }
    if (tail > 0) {
        int blocks = (tail + 63) / 64;
        sampler_fill_ones_tail<<<blocks, 64, 0, stream>>>(out, tail_start, n);
    }
}

// Round 2
// 10.168 us; speedup vs baseline: 1.1130x; 1.1130x over previous
//
#include <hip/hip_runtime.h>

// Sampler forward: y = stop_gradient(1 - p) + p  ==  (1 - p) + p  ==  1.0f
// exactly (p in [0,1]: Sterbenz for p>=0.5, and the re-add rounds back to 1.0
// for p<0.5 within 1 ulp; harness-measured absmax vs np reference = 0.0).
// The gather/segment-softmax pipeline is gradient-only dead code forward.
// Kernel = constant fill of out_size fp32 ones.
//
// Round-1 probe: 64 B per thread (4x float4), grid 1954 -> 489 blocks, to
// test whether block-dispatch count contributes to the ~10 us overhead floor.

__global__ void __launch_bounds__(256)
sampler_fill_ones_x4(float4* __restrict__ out4, int n4) {
    const float4 one = make_float4(1.0f, 1.0f, 1.0f, 1.0f);
    int i = (blockIdx.x * blockDim.x + threadIdx.x) * 4;
    if (i + 3 < n4) {
        out4[i + 0] = one;
        out4[i + 1] = one;
        out4[i + 2] = one;
        out4[i + 3] = one;
    } else {
        for (int j = i; j < n4; ++j) out4[j] = one;
    }
}

__global__ void __launch_bounds__(64)
sampler_fill_ones_tail(float* __restrict__ out, int start, int n) {
    int i = start + blockIdx.x * blockDim.x + threadIdx.x;
    if (i < n) out[i] = 1.0f;
}

extern "C" void kernel_launch(void* const* d_in, const int* in_sizes, int n_in,
                              void* d_out, int out_size, void* d_ws, size_t ws_size,
                              hipStream_t stream) {
    float* out = (float*)d_out;

    int n  = out_size;          // N_SAMP = 2,000,000
    int n4 = n >> 2;            // 500,000 float4 chunks
    int tail_start = n4 << 2;
    int tail = n - tail_start;  // 0 at this size

    if (n4 > 0) {
        // one thread per 4 float4s
        int threads_needed = (n4 + 3) / 4;             // 125,000
        int blocks = (threads_needed + 255) / 256;     // 489
        sampler_fill_ones_x4<<<blocks, 256, 0, stream>>>((float4*)out, n4);
    }
    if (tail > 0) {
        int blocks = (tail + 63) / 64;
        sampler_fill_ones_tail<<<blocks, 64, 0, stream>>>(out, tail_start, n);
    }
}